// Round 2
// baseline (152.789 us; speedup 1.0000x reference)
//
#include <hip/hip_runtime.h>
#include <math.h>

// Problem constants (reference: B,F,W,H,D = 128,1024,32,64,64)
#define B_   128
#define F_   1024
#define W_   32
#define H_   64
#define K4H  256          // 4*H
#define M_   (B_ * W_)    // 4096 rows of the gate GEMM
#define K2_  (2 * F_)     // 2048: fp32 split into interleaved (hi,lo) bf16 pairs

typedef __attribute__((ext_vector_type(8))) short  short8;  // 8 bf16 = 4 VGPRs (MFMA A/B frag)
typedef __attribute__((ext_vector_type(4))) float  f32x4;   // MFMA C/D frag

// ---------------------------------------------------------------------------
// fp32 -> (hi,lo) bf16 pair, packed little-endian into one uint:
//   short[0] = hi (k2 even), short[1] = lo (k2 odd).
// hi = RNE(v), lo = RNE(v - hi): v is reconstructed to ~2^-17 relative, so a
// plain bf16 MFMA over the doubled K computes the fp32 product near-exactly.
// ---------------------------------------------------------------------------
__device__ __forceinline__ unsigned bf16_rne(float v) {
  unsigned u = __float_as_uint(v);
  return (u + 0x7FFFu + ((u >> 16) & 1u)) >> 16;
}
__device__ __forceinline__ unsigned pack_hilo(float v) {
  unsigned hi = bf16_rne(v);
  float    hf = __uint_as_float(hi << 16);
  unsigned lo = bf16_rne(v - hf);
  return hi | (lo << 16);
}

// ---------------------------------------------------------------------------
// Wx [F,4H] fp32  ->  B2 [4H][K2/2] uints (transposed, hi/lo packed).
// B2 row n holds k2-consecutive data so MFMA B-frags (k-consecutive per lane)
// read contiguously. Tiny: 1 MB out.
// ---------------------------------------------------------------------------
__global__ __launch_bounds__(256) void conv_w(const float* __restrict__ Wx,
                                              unsigned* __restrict__ B2) {
  __shared__ unsigned T[256][17];  // [n][f_local], +1 pad
  const int tid = threadIdx.x;
  const int f0  = blockIdx.x * 16;
#pragma unroll
  for (int i = 0; i < 4; ++i) {
    int l = tid + i * 256;          // 1024 float4 slots = 16 f x 256 n
    int n0 = (l & 63) * 4;
    int fl = l >> 6;                // 0..15
    float4 v = *(const float4*)&Wx[(size_t)(f0 + fl) * K4H + n0];
    T[n0 + 0][fl] = pack_hilo(v.x);
    T[n0 + 1][fl] = pack_hilo(v.y);
    T[n0 + 2][fl] = pack_hilo(v.z);
    T[n0 + 3][fl] = pack_hilo(v.w);
  }
  __syncthreads();
#pragma unroll
  for (int i = 0; i < 4; ++i) {
    int l  = tid + i * 256;         // 1024 uint4 slots = 256 n x 4
    int c4 = (l & 3) * 4;
    int n  = l >> 2;
    uint4 o;
    o.x = T[n][c4 + 0]; o.y = T[n][c4 + 1]; o.z = T[n][c4 + 2]; o.w = T[n][c4 + 3];
    *(uint4*)&B2[(size_t)n * (K2_ / 2) + f0 + c4] = o;
  }
}

// ---------------------------------------------------------------------------
// Gate GEMM via MFMA: Gp[s][m][k] partial = sum_{f in split s} x[b,f,t]*Wx[f,k]
// (attention softmax over a size-1 axis == 1, so the projection is hoisted).
// Block tile 128x128, wave tile 64x64 (4x4 of 16x16x32 MFMAs), K-split S.
// x is converted/transposed to hi/lo bf16 inside LDS staging (fused).
// LDS rows padded to 144 B to break power-of-2 bank strides.
// ---------------------------------------------------------------------------
__global__ __launch_bounds__(256) void gemm_mfma(
    const float* __restrict__ x,      // [B, F, W]
    const unsigned* __restrict__ B2,  // [4H][K2/2] packed
    float* __restrict__ Gp, int S) {  // [S][M][4H] partials
  __shared__ unsigned lA[128 * 36];   // [m][36 uints]: 64 k2 (32 f) + 16B pad
  __shared__ unsigned lB[128 * 36];   // [n][36 uints]
  const int tid   = threadIdx.x;
  const int mtile = blockIdx.x;       // 0..31
  const int ntile = blockIdx.y;       // 0..1
  const int s     = blockIdx.z;       // 0..S-1
  const int NIT   = 32 / S;           // stage iterations of 64 k2 (32 f) each
  const int wv = tid >> 6, lane = tid & 63;
  const int wm = wv & 1, wn = wv >> 1;     // wave -> 64x64 quadrant
  const int lm = lane & 15, q = lane >> 4; // MFMA lane decomposition

  f32x4 acc[4][4];
#pragma unroll
  for (int a = 0; a < 4; ++a)
#pragma unroll
    for (int bb = 0; bb < 4; ++bb) acc[a][bb] = (f32x4){0.f, 0.f, 0.f, 0.f};

  const int b0 = mtile * 4;  // 4 batch elements per 128-row tile (m = b*32+t)
  float4 ax[4];
  uint4  bxr[4];

  auto prefetch = [&](int iter) {
    const int f0 = (s * NIT + iter) * 32;
#pragma unroll
    for (int i = 0; i < 4; ++i) {
      int l  = tid + i * 256;       // 1024 float4 = 8 t-groups x 32 f x 4 b
      int t0 = (l & 7) * 4;
      int fl = (l >> 3) & 31;
      int bl = l >> 8;
      ax[i] = *(const float4*)&x[(((size_t)(b0 + bl)) * F_ + (f0 + fl)) * W_ + t0];
    }
#pragma unroll
    for (int i = 0; i < 4; ++i) {
      int l   = tid + i * 256;      // 1024 uint4 = 128 n x 8
      int c16 = l & 7;
      int nl  = l >> 3;
      bxr[i] = *(const uint4*)&B2[(size_t)(ntile * 128 + nl) * (K2_ / 2) + f0 + c16 * 4];
    }
  };

  prefetch(0);
  for (int iter = 0; iter < NIT; ++iter) {
    __syncthreads();                 // previous iter's frag reads done
#pragma unroll
    for (int i = 0; i < 4; ++i) {    // A: convert + transpose (t -> row m)
      int l  = tid + i * 256;
      int t0 = (l & 7) * 4;
      int fl = (l >> 3) & 31;
      int bl = l >> 8;
      int m  = bl * 32 + t0;
      lA[(m + 0) * 36 + fl] = pack_hilo(ax[i].x);
      lA[(m + 1) * 36 + fl] = pack_hilo(ax[i].y);
      lA[(m + 2) * 36 + fl] = pack_hilo(ax[i].z);
      lA[(m + 3) * 36 + fl] = pack_hilo(ax[i].w);
    }
#pragma unroll
    for (int i = 0; i < 4; ++i) {    // B: straight copy (pre-packed)
      int l   = tid + i * 256;
      int c16 = l & 7;
      int nl  = l >> 3;
      *(uint4*)&lB[nl * 36 + c16 * 4] = bxr[i];
    }
    __syncthreads();
    if (iter + 1 < NIT) prefetch(iter + 1);  // overlap global loads with MFMA
#pragma unroll
    for (int step = 0; step < 2; ++step) {   // 2 x K=32 MFMA steps per stage
      short8 aF[4], bF[4];
#pragma unroll
      for (int mt = 0; mt < 4; ++mt) {
        int row = wm * 64 + mt * 16 + lm;    // A[m=lane&15][k=q*8+j]
        aF[mt] = *(const short8*)&lA[row * 36 + step * 16 + q * 4];
      }
#pragma unroll
      for (int nt = 0; nt < 4; ++nt) {
        int row = wn * 64 + nt * 16 + lm;    // B[k=q*8+j][n=lane&15]
        bF[nt] = *(const short8*)&lB[row * 36 + step * 16 + q * 4];
      }
#pragma unroll
      for (int mt = 0; mt < 4; ++mt)
#pragma unroll
        for (int nt = 0; nt < 4; ++nt)
          acc[mt][nt] = __builtin_amdgcn_mfma_f32_16x16x32_bf16(
              aF[mt], bF[nt], acc[mt][nt], 0, 0, 0);
    }
  }
  // epilogue: C/D layout col=lane&15, row=q*4+reg  [m89-verified]
  float* Gs = Gp + (size_t)s * ((size_t)M_ * K4H);
#pragma unroll
  for (int mt = 0; mt < 4; ++mt)
#pragma unroll
    for (int nt = 0; nt < 4; ++nt)
#pragma unroll
      for (int r = 0; r < 4; ++r) {
        int m = mtile * 128 + wm * 64 + mt * 16 + q * 4 + r;
        int n = ntile * 128 + wn * 64 + nt * 16 + lm;
        Gs[(size_t)m * K4H + n] = acc[mt][nt][r];
      }
}

// ---------------------------------------------------------------------------
// Sequential LSTM. One block (128 thr = 2 waves) per batch element.
// Thread (w,u): gates kA=w*128+u, kB=kA+64  (w0: i,f;  w1: g,o).
// h lives redundantly in BOTH waves' lanes (lane u = h[u]); the h.Wh dot uses
// v_readlane broadcast (SALU) -> zero LDS traffic. c updated redundantly in
// both waves -> only ONE barrier per step (activation exchange, dbl-buffered).
// Next-step G partials are prefetched before the dot. Output = CELL state
// (reference's s,h swap).
// ---------------------------------------------------------------------------
__device__ __forceinline__ float bcastlane(float v, int l) {
  return __uint_as_float(__builtin_amdgcn_readlane(__float_as_uint(v), l));
}
__device__ __forceinline__ float sigm(float v)  { return 1.f / (1.f + __expf(-v)); }
__device__ __forceinline__ float tanh_f(float v){ return 1.f - 2.f / (__expf(2.f * v) + 1.f); }

__global__ __launch_bounds__(128) void lstm_seq(
    const float* __restrict__ Gp, const float* __restrict__ Wh,
    const float* __restrict__ bl, float* __restrict__ out, int S) {
  __shared__ float2 ex[2][2][64];  // [t-parity][wave][u]
  const int b = blockIdx.x, tid = threadIdx.x;
  const int w = tid >> 6, u = tid & 63;
  const int kA = w * 128 + u, kB = kA + 64;

  float wA[64], wB[64];            // two Wh columns, register-resident
#pragma unroll
  for (int j = 0; j < 64; ++j) {
    wA[j] = Wh[j * K4H + kA];
    wB[j] = Wh[j * K4H + kB];
  }
  const float bA = bl[kA], bB = bl[kB];
  const size_t base = (size_t)b * W_ * K4H;
  const size_t sstr = (size_t)M_ * K4H;

  float h = 0.f, c = 0.f;
  float cA[4] = {0, 0, 0, 0}, cB[4] = {0, 0, 0, 0};
  for (int ss = 0; ss < S; ++ss) {
    cA[ss] = Gp[ss * sstr + base + kA];
    cB[ss] = Gp[ss * sstr + base + kB];
  }
  for (int t = 0; t < W_; ++t) {
    float nA[4] = {0, 0, 0, 0}, nB[4] = {0, 0, 0, 0};
    if (t + 1 < W_) {
      for (int ss = 0; ss < S; ++ss) {   // prefetch next step's G partials
        nA[ss] = Gp[ss * sstr + base + (t + 1) * K4H + kA];
        nB[ss] = Gp[ss * sstr + base + (t + 1) * K4H + kB];
      }
    }
    float gA = bA + ((cA[0] + cA[1]) + (cA[2] + cA[3]));
    float gB = bB + ((cB[0] + cB[1]) + (cB[2] + cB[3]));
    float a0 = gA, a1 = 0, a2 = 0, a3 = 0;   // 4-way split chains
    float e0 = gB, e1 = 0, e2 = 0, e3 = 0;
#pragma unroll
    for (int j = 0; j < 64; j += 4) {
      float h0 = bcastlane(h, j),     h1 = bcastlane(h, j + 1);
      float h2 = bcastlane(h, j + 2), h3 = bcastlane(h, j + 3);
      a0 = fmaf(h0, wA[j],     a0);  e0 = fmaf(h0, wB[j],     e0);
      a1 = fmaf(h1, wA[j + 1], a1);  e1 = fmaf(h1, wB[j + 1], e1);
      a2 = fmaf(h2, wA[j + 2], a2);  e2 = fmaf(h2, wB[j + 2], e2);
      a3 = fmaf(h3, wA[j + 3], a3);  e3 = fmaf(h3, wB[j + 3], e3);
    }
    gA = (a0 + a1) + (a2 + a3);
    gB = (e0 + e1) + (e2 + e3);
    float eA, eB;                     // wave-uniform branch
    if (w == 0) { eA = sigm(gA);   eB = sigm(gB); }   // i, f
    else        { eA = tanh_f(gA); eB = sigm(gB); }   // g, o
    ex[t & 1][w][u] = make_float2(eA, eB);
    __syncthreads();                  // the single barrier per step
    float2 o = ex[t & 1][1 - w][u];
    float si = (w == 0) ? eA : o.x;
    float sf = (w == 0) ? eB : o.y;
    float tg = (w == 0) ? o.x : eA;
    float so = (w == 0) ? o.y : eB;
    c = fmaf(sf, c, si * tg);         // identical in both waves
    h = so * tanh_f(c);
    if (w == 0) out[((size_t)b * W_ + t) * H_ + u] = c;  // cell state out
#pragma unroll
    for (int ss = 0; ss < 4; ++ss) { cA[ss] = nA[ss]; cB[ss] = nB[ss]; }
  }
}

// ---------------------------------------------------------------------------
extern "C" void kernel_launch(void* const* d_in, const int* in_sizes, int n_in,
                              void* d_out, int out_size, void* d_ws, size_t ws_size,
                              hipStream_t stream) {
  // 0:x 1:W_state 2:b_state 3:W_in 4:w_attn 5:b_attn 6:Wx 7:Wh 8:b_lstm
  const float* x      = (const float*)d_in[0];
  const float* Wx     = (const float*)d_in[6];
  const float* Wh     = (const float*)d_in[7];
  const float* b_lstm = (const float*)d_in[8];
  float* out = (float*)d_out;

  const size_t gbytes = (size_t)M_ * K4H * sizeof(float);  // 4 MB per partial
  int S;                        // K-split factor, degrade if ws is small
  if      (ws_size >= 4 * gbytes + (1u << 20)) S = 4;
  else if (ws_size >= 2 * gbytes + (1u << 20)) S = 2;
  else                                         S = 1;
  float*    Gp = (float*)d_ws;                                // [S][M][4H]
  unsigned* B2 = (unsigned*)((char*)d_ws + (size_t)S * gbytes);  // 1 MB

  conv_w  <<<dim3(64),        dim3(256), 0, stream>>>(Wx, B2);
  gemm_mfma<<<dim3(32, 2, S), dim3(256), 0, stream>>>(x, B2, Gp, S);
  lstm_seq<<<dim3(B_),        dim3(128), 0, stream>>>(Gp, Wh, b_lstm, out, S);
}

// Round 3
// 143.441 us; speedup vs baseline: 1.0652x; 1.0652x over previous
//
#include <hip/hip_runtime.h>
#include <math.h>

// Problem constants (reference: B,F,W,H,D = 128,1024,32,64,64)
#define B_   128
#define F_   1024
#define W_   32
#define H_   64
#define K4H  256          // 4*H
#define M_   (B_ * W_)    // 4096 rows of the gate GEMM
#define K2_  (2 * F_)     // 2048: fp32 split into interleaved (hi,lo) bf16 pairs

typedef __attribute__((ext_vector_type(8))) short  short8;  // 8 bf16 (MFMA A/B frag)
typedef __attribute__((ext_vector_type(4))) float  f32x4;   // MFMA C/D frag

// ---------------------------------------------------------------------------
// fp32 -> (hi,lo) bf16 pair packed into one uint: short[0]=hi (k2 even),
// short[1]=lo (k2 odd). hi=RNE(v), lo=RNE(v-hi) -> fp32 product via plain
// bf16 MFMA over doubled K, near-exact.
// ---------------------------------------------------------------------------
__device__ __forceinline__ unsigned bf16_rne(float v) {
  unsigned u = __float_as_uint(v);
  return (u + 0x7FFFu + ((u >> 16) & 1u)) >> 16;
}
__device__ __forceinline__ unsigned pack_hilo(float v) {
  unsigned hi = bf16_rne(v);
  float    hf = __uint_as_float(hi << 16);
  unsigned lo = bf16_rne(v - hf);
  return hi | (lo << 16);
}

// ---------------------------------------------------------------------------
// Wx [F,4H] fp32 -> B2 [4H][K2/2] uints (transposed, hi/lo packed).
// ---------------------------------------------------------------------------
__global__ __launch_bounds__(256) void conv_w(const float* __restrict__ Wx,
                                              unsigned* __restrict__ B2) {
  __shared__ unsigned T[256][17];  // [n][f_local], +1 pad
  const int tid = threadIdx.x;
  const int f0  = blockIdx.x * 16;
#pragma unroll
  for (int i = 0; i < 4; ++i) {
    int l = tid + i * 256;          // 1024 float4 slots = 16 f x 64 n-groups
    int n0 = (l & 63) * 4;
    int fl = l >> 6;                // 0..15
    float4 v = *(const float4*)&Wx[(size_t)(f0 + fl) * K4H + n0];
    T[n0 + 0][fl] = pack_hilo(v.x);
    T[n0 + 1][fl] = pack_hilo(v.y);
    T[n0 + 2][fl] = pack_hilo(v.z);
    T[n0 + 3][fl] = pack_hilo(v.w);
  }
  __syncthreads();
#pragma unroll
  for (int i = 0; i < 4; ++i) {
    int l  = tid + i * 256;         // 1024 uint4 slots = 256 n x 4
    int c4 = (l & 3) * 4;
    int n  = l >> 2;
    uint4 o;
    o.x = T[n][c4 + 0]; o.y = T[n][c4 + 1]; o.z = T[n][c4 + 2]; o.w = T[n][c4 + 3];
    *(uint4*)&B2[(size_t)n * (K2_ / 2) + f0 + c4] = o;
  }
}

// ---------------------------------------------------------------------------
// Gate GEMM via MFMA (attention softmax over size-1 axis == 1, projection
// hoisted out of the recurrence). Block tile 128(M)x64(N), 4 waves with
// 64x32 wave tiles (4x2 of 16x16x32 bf16 MFMAs), K-split S (template).
// Grid (32, 4, S) = 256 blocks at S=2. x converted to hi/lo bf16 in staging.
// __launch_bounds__(256,2): VGPR cap 256 -> acc/frags stay in registers.
// ---------------------------------------------------------------------------
template <int S>
__global__ __launch_bounds__(256, 2) void gemm_mfma(
    const float* __restrict__ x,      // [B, F, W]
    const unsigned* __restrict__ B2,  // [4H][K2/2] packed
    float* __restrict__ Gp) {         // [S][M][4H] partials
  constexpr int NIT = 32 / S;         // stage iters of 32 f (64 k2) each
  __shared__ unsigned lA[128 * 36];   // [m][36 uints]: 32 data + 4 pad
  __shared__ unsigned lB[64 * 36];    // [n][36 uints]
  const int tid   = threadIdx.x;
  const int mtile = blockIdx.x;       // 0..31 (4 batches per tile)
  const int ntile = blockIdx.y;       // 0..3  (64 gate cols)
  const int s     = blockIdx.z;       // 0..S-1
  const int wv = tid >> 6, lane = tid & 63;
  const int wm = wv & 1, wn = wv >> 1;      // wave -> 64x32 quadrant
  const int lm = lane & 15, q = lane >> 4;  // MFMA lane decomposition

  f32x4 acc[4][2];
#pragma unroll
  for (int a = 0; a < 4; ++a)
#pragma unroll
    for (int bb = 0; bb < 2; ++bb) acc[a][bb] = (f32x4){0.f, 0.f, 0.f, 0.f};

  const int b0 = mtile * 4;
  float4 ax[4];
  uint4  bxr[2];

  auto prefetch = [&](int iter) {
    const int f0 = (s * NIT + iter) * 32;
#pragma unroll
    for (int i = 0; i < 4; ++i) {
      int l  = tid + i * 256;       // 1024 float4 = 4 b x 32 f x 8 t-groups
      int t0 = (l & 7) * 4;
      int fl = (l >> 3) & 31;
      int bl = l >> 8;
      ax[i] = *(const float4*)&x[(((size_t)(b0 + bl)) * F_ + (f0 + fl)) * W_ + t0];
    }
#pragma unroll
    for (int i = 0; i < 2; ++i) {
      int l   = tid + i * 256;      // 512 uint4 = 64 n x 8
      int c16 = l & 7;
      int nl  = l >> 3;
      bxr[i] = *(const uint4*)&B2[(size_t)(ntile * 64 + nl) * (K2_ / 2) + f0 + c16 * 4];
    }
  };

  prefetch(0);
  for (int iter = 0; iter < NIT; ++iter) {
    __syncthreads();                 // previous iter's frag reads done
#pragma unroll
    for (int i = 0; i < 4; ++i) {    // A: convert + transpose (t -> row m)
      int l  = tid + i * 256;
      int t0 = (l & 7) * 4;
      int fl = (l >> 3) & 31;
      int bl = l >> 8;
      int m  = bl * 32 + t0;
      lA[(m + 0) * 36 + fl] = pack_hilo(ax[i].x);
      lA[(m + 1) * 36 + fl] = pack_hilo(ax[i].y);
      lA[(m + 2) * 36 + fl] = pack_hilo(ax[i].z);
      lA[(m + 3) * 36 + fl] = pack_hilo(ax[i].w);
    }
#pragma unroll
    for (int i = 0; i < 2; ++i) {    // B: straight copy (pre-packed)
      int l   = tid + i * 256;
      int c16 = l & 7;
      int nl  = l >> 3;
      *(uint4*)&lB[nl * 36 + c16 * 4] = bxr[i];
    }
    __syncthreads();
    if (iter + 1 < NIT) prefetch(iter + 1);  // overlap globals with MFMA
#pragma unroll
    for (int step = 0; step < 2; ++step) {   // 2 x K2=32 MFMA steps
      short8 aF[4], bF[2];
#pragma unroll
      for (int mt = 0; mt < 4; ++mt) {
        int row = wm * 64 + mt * 16 + lm;    // A[m=lane&15][k=q*8+j]
        aF[mt] = *(const short8*)&lA[row * 36 + step * 16 + q * 4];
      }
#pragma unroll
      for (int nt = 0; nt < 2; ++nt) {
        int row = wn * 32 + nt * 16 + lm;    // B[k=q*8+j][n=lane&15]
        bF[nt] = *(const short8*)&lB[row * 36 + step * 16 + q * 4];
      }
#pragma unroll
      for (int mt = 0; mt < 4; ++mt)
#pragma unroll
        for (int nt = 0; nt < 2; ++nt)
          acc[mt][nt] = __builtin_amdgcn_mfma_f32_16x16x32_bf16(
              aF[mt], bF[nt], acc[mt][nt], 0, 0, 0);
    }
  }
  // epilogue: C/D layout col=lane&15, row=q*4+reg  [m89-verified]
  float* Gs = Gp + (size_t)s * ((size_t)M_ * K4H);
#pragma unroll
  for (int mt = 0; mt < 4; ++mt)
#pragma unroll
    for (int nt = 0; nt < 2; ++nt)
#pragma unroll
      for (int r = 0; r < 4; ++r) {
        int m = mtile * 128 + wm * 64 + mt * 16 + q * 4 + r;
        int n = ntile * 64 + wn * 32 + nt * 16 + lm;
        Gs[(size_t)m * K4H + n] = acc[mt][nt][r];
      }
}

// ---------------------------------------------------------------------------
// Sequential LSTM: ONE WAVE per batch element, zero barriers, zero LDS.
// Thread u owns all four gates of hidden unit u (k = u, u+64, u+128, u+192
// = i_u, f_u, g_u, o_u), so the whole cell update is in-lane. h_j broadcasts
// via v_readlane (imm lane after unroll). 256 Wh weights per thread stay in
// VGPRs thanks to __launch_bounds__(64,1) (cap 512). Next-step G partials
// prefetched. Output = CELL state (reference's s,h swap).
// ---------------------------------------------------------------------------
__device__ __forceinline__ float bcastlane(float v, int l) {
  return __uint_as_float(__builtin_amdgcn_readlane(__float_as_uint(v), l));
}
__device__ __forceinline__ float sigm(float v)   { return 1.f / (1.f + __expf(-v)); }
__device__ __forceinline__ float tanh_f(float v) { return 1.f - 2.f / (__expf(2.f * v) + 1.f); }

template <int S>
__global__ __launch_bounds__(64, 1) void lstm_seq(
    const float* __restrict__ Gp, const float* __restrict__ Wh,
    const float* __restrict__ bl, float* __restrict__ out) {
  const int b = blockIdx.x, u = threadIdx.x;  // u in [0,64)

  float wI[64], wF[64], wG[64], wO[64];       // 256 VGPRs of Wh
#pragma unroll
  for (int j = 0; j < 64; ++j) {
    const float* r = Wh + j * K4H;
    wI[j] = r[u];
    wF[j] = r[u + 64];
    wG[j] = r[u + 128];
    wO[j] = r[u + 192];
  }
  const float bI = bl[u], bF = bl[u + 64], bG = bl[u + 128], bO = bl[u + 192];
  const size_t base = (size_t)b * W_ * K4H;
  const size_t sstr = (size_t)M_ * K4H;

  float h = 0.f, c = 0.f;
  float pI = 0.f, pF = 0.f, pG = 0.f, pO = 0.f;
#pragma unroll
  for (int ss = 0; ss < S; ++ss) {
    const float* g0 = Gp + ss * sstr + base;
    pI += g0[u]; pF += g0[u + 64]; pG += g0[u + 128]; pO += g0[u + 192];
  }
  for (int t = 0; t < W_; ++t) {
    float nI = 0.f, nF = 0.f, nG = 0.f, nO = 0.f;
    if (t + 1 < W_) {                          // prefetch next step's G
#pragma unroll
      for (int ss = 0; ss < S; ++ss) {
        const float* gn = Gp + ss * sstr + base + (size_t)(t + 1) * K4H;
        nI += gn[u]; nF += gn[u + 64]; nG += gn[u + 128]; nO += gn[u + 192];
      }
    }
    float aI = pI + bI, aF2 = pF + bF, aG = pG + bG, aO = pO + bO;
#pragma unroll
    for (int j = 0; j < 64; ++j) {             // 4 independent FMA chains
      float hj = bcastlane(h, j);
      aI  = fmaf(hj, wI[j], aI);
      aF2 = fmaf(hj, wF[j], aF2);
      aG  = fmaf(hj, wG[j], aG);
      aO  = fmaf(hj, wO[j], aO);
    }
    float si = sigm(aI), sf = sigm(aF2), tg = tanh_f(aG), so = sigm(aO);
    c = fmaf(sf, c, si * tg);
    h = so * tanh_f(c);
    out[((size_t)b * W_ + t) * H_ + u] = c;    // cell state out
    pI = nI; pF = nF; pG = nG; pO = nO;
  }
}

// ---------------------------------------------------------------------------
extern "C" void kernel_launch(void* const* d_in, const int* in_sizes, int n_in,
                              void* d_out, int out_size, void* d_ws, size_t ws_size,
                              hipStream_t stream) {
  // 0:x 1:W_state 2:b_state 3:W_in 4:w_attn 5:b_attn 6:Wx 7:Wh 8:b_lstm
  const float* x      = (const float*)d_in[0];
  const float* Wx     = (const float*)d_in[6];
  const float* Wh     = (const float*)d_in[7];
  const float* b_lstm = (const float*)d_in[8];
  float* out = (float*)d_out;

  const size_t gbytes = (size_t)M_ * K4H * sizeof(float);  // 4 MB per partial

  if (ws_size >= 2 * gbytes + (1u << 20)) {     // S = 2 (measured path)
    float*    Gp = (float*)d_ws;
    unsigned* B2 = (unsigned*)((char*)d_ws + 2 * gbytes);
    conv_w      <<<dim3(64),       dim3(256), 0, stream>>>(Wx, B2);
    gemm_mfma<2><<<dim3(32, 4, 2), dim3(256), 0, stream>>>(x, B2, Gp);
    lstm_seq<2> <<<dim3(B_),       dim3(64),  0, stream>>>(Gp, Wh, b_lstm, out);
  } else {                                      // S = 1 fallback (5 MB ws)
    float*    Gp = (float*)d_ws;
    unsigned* B2 = (unsigned*)((char*)d_ws + gbytes);
    conv_w      <<<dim3(64),       dim3(256), 0, stream>>>(Wx, B2);
    gemm_mfma<1><<<dim3(32, 4, 1), dim3(256), 0, stream>>>(x, B2, Gp);
    lstm_seq<1> <<<dim3(B_),       dim3(64),  0, stream>>>(Gp, Wh, b_lstm, out);
  }
}

// Round 4
// 121.259 us; speedup vs baseline: 1.2600x; 1.1829x over previous
//
#include <hip/hip_runtime.h>
#include <math.h>

// Problem constants (reference: B,F,W,H,D = 128,1024,32,64,64)
#define B_   128
#define F_   1024
#define W_   32
#define H_   64
#define K4H  256          // 4*H
#define M_   (B_ * W_)    // 4096 rows of the gate GEMM
#define K2_  (2 * F_)     // 2048: fp32 split into interleaved (hi,lo) bf16 pairs

typedef __attribute__((ext_vector_type(8))) short  short8;  // 8 bf16 (MFMA A/B frag)
typedef __attribute__((ext_vector_type(4))) float  f32x4;   // MFMA C/D frag

// ---------------------------------------------------------------------------
// fp32 -> (hi,lo) bf16 pair packed into one uint: short[0]=hi (k2 even),
// short[1]=lo (k2 odd). hi=RNE(v), lo=RNE(v-hi) -> fp32 product via plain
// bf16 MFMA over doubled K, near-exact.
// ---------------------------------------------------------------------------
__device__ __forceinline__ unsigned bf16_rne(float v) {
  unsigned u = __float_as_uint(v);
  return (u + 0x7FFFu + ((u >> 16) & 1u)) >> 16;
}
__device__ __forceinline__ unsigned pack_hilo(float v) {
  unsigned hi = bf16_rne(v);
  float    hf = __uint_as_float(hi << 16);
  unsigned lo = bf16_rne(v - hf);
  return hi | (lo << 16);
}

// ---------------------------------------------------------------------------
// Wx [F,4H] fp32 -> B2 [4H][K2/2] uints (transposed, hi/lo packed).
// ---------------------------------------------------------------------------
__global__ __launch_bounds__(256) void conv_w(const float* __restrict__ Wx,
                                              unsigned* __restrict__ B2) {
  __shared__ unsigned T[256][17];  // [n][f_local], +1 pad
  const int tid = threadIdx.x;
  const int f0  = blockIdx.x * 16;
#pragma unroll
  for (int i = 0; i < 4; ++i) {
    int l = tid + i * 256;          // 1024 float4 slots = 16 f x 64 n-groups
    int n0 = (l & 63) * 4;
    int fl = l >> 6;                // 0..15
    float4 v = *(const float4*)&Wx[(size_t)(f0 + fl) * K4H + n0];
    T[n0 + 0][fl] = pack_hilo(v.x);
    T[n0 + 1][fl] = pack_hilo(v.y);
    T[n0 + 2][fl] = pack_hilo(v.z);
    T[n0 + 3][fl] = pack_hilo(v.w);
  }
  __syncthreads();
#pragma unroll
  for (int i = 0; i < 4; ++i) {
    int l  = tid + i * 256;         // 1024 uint4 slots = 256 n x 4
    int c4 = (l & 3) * 4;
    int n  = l >> 2;
    uint4 o;
    o.x = T[n][c4 + 0]; o.y = T[n][c4 + 1]; o.z = T[n][c4 + 2]; o.w = T[n][c4 + 3];
    *(uint4*)&B2[(size_t)n * (K2_ / 2) + f0 + c4] = o;
  }
}

// ---------------------------------------------------------------------------
// Gate GEMM via MFMA (attention softmax over size-1 axis == 1, projection
// hoisted out of the recurrence). Block tile 128(M)x128(N), 4 waves with
// 64x64 wave tiles (4x4 of 16x16x32 bf16 MFMAs = 32 MFMA/stage), K-split S.
// Grid (32, 2, S) = 256 blocks at S=4. x converted to hi/lo bf16 in staging;
// A-writes XOR-reordered to spread LDS banks. 36-uint row stride (pad) keeps
// the b128 frag reads conflict-free (verified 0 conflicts in R1).
// __launch_bounds__(256,1): VGPR cap 512 -> nothing spills (est ~170).
// ---------------------------------------------------------------------------
template <int S>
__global__ __launch_bounds__(256, 1) void gemm_mfma(
    const float* __restrict__ x,      // [B, F, W]
    const unsigned* __restrict__ B2,  // [4H][K2/2] packed
    float* __restrict__ Gp) {         // [S][M][4H] partials
  constexpr int NIT = 32 / S;         // stage iters of 32 f (64 k2) each
  __shared__ unsigned lA[128 * 36];
  __shared__ unsigned lB[128 * 36];
  const int tid   = threadIdx.x;
  const int mtile = blockIdx.x;       // 0..31 (4 batches per tile)
  const int ntile = blockIdx.y;       // 0..1  (128 gate cols)
  const int s     = blockIdx.z;       // 0..S-1
  const int wv = tid >> 6, lane = tid & 63;
  const int wm = wv & 1, wn = wv >> 1;      // wave -> 64x64 quadrant
  const int lm = lane & 15, q = lane >> 4;  // MFMA lane decomposition

  f32x4 acc[4][4];
#pragma unroll
  for (int a = 0; a < 4; ++a)
#pragma unroll
    for (int bb = 0; bb < 4; ++bb) acc[a][bb] = (f32x4){0.f, 0.f, 0.f, 0.f};

  const int b0 = mtile * 4;
  float4 ax[4];
  uint4  bxr[4];

  auto prefetch = [&](int iter) {
    const int f0 = (s * NIT + iter) * 32;
#pragma unroll
    for (int i = 0; i < 4; ++i) {
      int l  = tid + i * 256;       // 1024 float4 = 4 b x 32 f x 8 t-groups
      int t0 = (l & 7) * 4;
      int fl = (l >> 3) & 31;
      int bl = l >> 8;
      ax[i] = *(const float4*)&x[(((size_t)(b0 + bl)) * F_ + (f0 + fl)) * W_ + t0];
    }
#pragma unroll
    for (int i = 0; i < 4; ++i) {
      int l   = tid + i * 256;      // 1024 uint4 = 128 n x 8
      int c16 = l & 7;
      int nl  = l >> 3;
      bxr[i] = *(const uint4*)&B2[(size_t)(ntile * 128 + nl) * (K2_ / 2) + f0 + c16 * 4];
    }
  };

  prefetch(0);
  const int jx = (tid >> 3) & 3;     // XOR bank-spread for A's b32 writes
  for (int iter = 0; iter < NIT; ++iter) {
    __syncthreads();                 // previous iter's frag reads done
#pragma unroll
    for (int i = 0; i < 4; ++i) {    // A: convert + transpose (t -> row m)
      int l  = tid + i * 256;
      int t0 = (l & 7) * 4;
      int fl = (l >> 3) & 31;
      int bl = l >> 8;
      int m0 = bl * 32 + t0;
      float vals[4] = {ax[i].x, ax[i].y, ax[i].z, ax[i].w};
#pragma unroll
      for (int j = 0; j < 4; ++j) {
        int jj = j ^ jx;
        lA[(m0 + jj) * 36 + fl] = pack_hilo(vals[jj]);
      }
    }
#pragma unroll
    for (int i = 0; i < 4; ++i) {    // B: straight b128 copy (pre-packed)
      int l   = tid + i * 256;
      int c16 = l & 7;
      int nl  = l >> 3;
      *(uint4*)&lB[nl * 36 + c16 * 4] = bxr[i];
    }
    __syncthreads();
    if (iter + 1 < NIT) prefetch(iter + 1);  // overlap globals with MFMA
#pragma unroll
    for (int step = 0; step < 2; ++step) {   // 2 x K2=32 MFMA steps
      short8 aF[4], bF[4];
#pragma unroll
      for (int mt = 0; mt < 4; ++mt) {
        int row = wm * 64 + mt * 16 + lm;    // A[m=lane&15][k=q*8+j]
        aF[mt] = *(const short8*)&lA[row * 36 + step * 16 + q * 4];
      }
#pragma unroll
      for (int nt = 0; nt < 4; ++nt) {
        int row = wn * 64 + nt * 16 + lm;    // B[k=q*8+j][n=lane&15]
        bF[nt] = *(const short8*)&lB[row * 36 + step * 16 + q * 4];
      }
#pragma unroll
      for (int mt = 0; mt < 4; ++mt)
#pragma unroll
        for (int nt = 0; nt < 4; ++nt)
          acc[mt][nt] = __builtin_amdgcn_mfma_f32_16x16x32_bf16(
              aF[mt], bF[nt], acc[mt][nt], 0, 0, 0);
    }
  }
  // epilogue: C/D layout col=lane&15, row=q*4+reg  [m89-verified]
  float* Gs = Gp + (size_t)s * ((size_t)M_ * K4H);
#pragma unroll
  for (int mt = 0; mt < 4; ++mt)
#pragma unroll
    for (int nt = 0; nt < 4; ++nt)
#pragma unroll
      for (int r = 0; r < 4; ++r) {
        int m = mtile * 128 + wm * 64 + mt * 16 + q * 4 + r;
        int n = ntile * 128 + wn * 64 + nt * 16 + lm;
        Gs[(size_t)m * K4H + n] = acc[mt][nt][r];
      }
}

// ---------------------------------------------------------------------------
// Sequential LSTM: 256 threads (4 waves) per batch element. Thread (w,u)
// owns ONE gate column k = w*64+u (wave 0/1/2/3 = i/f/g/o -> the tanh branch
// is wave-uniform). 64 Wh weights per thread (64 VGPRs -- fits the 256-arch-
// VGPR file with huge margin, unlike the 256-weight variant that spilled at
// VGPR_Count=144). h replicated per wave (lane u = h[u]); dot uses
// v_readlane broadcast, 4 split FMA chains. One barrier/step (parity-
// double-buffered activation exchange); c,h updated redundantly in all
// waves. Next-step G partials prefetched. Output = CELL state (s,h swap).
// ---------------------------------------------------------------------------
__device__ __forceinline__ float bcastlane(float v, int l) {
  return __uint_as_float(__builtin_amdgcn_readlane(__float_as_uint(v), l));
}
__device__ __forceinline__ float sigm(float v)   { return 1.f / (1.f + __expf(-v)); }
__device__ __forceinline__ float tanh_f(float v) { return 1.f - 2.f / (__expf(2.f * v) + 1.f); }

template <int S>
__global__ __launch_bounds__(256, 1) void lstm_seq(
    const float* __restrict__ Gp, const float* __restrict__ Wh,
    const float* __restrict__ bl, float* __restrict__ out) {
  __shared__ float sact[2][4][64];            // [t-parity][gate-wave][u]
  const int b = blockIdx.x, tid = threadIdx.x;
  const int w = tid >> 6, u = tid & 63;
  const int k = w * 64 + u;                   // gate column

  float wc[64];                               // Wh column k, register-resident
#pragma unroll
  for (int j = 0; j < 64; ++j) wc[j] = Wh[j * K4H + k];
  const float bk = bl[k];
  const size_t base = (size_t)b * W_ * K4H + k;
  const size_t sstr = (size_t)M_ * K4H;

  float h = 0.f, c = 0.f;
  float p = 0.f;
#pragma unroll
  for (int ss = 0; ss < S; ++ss) p += Gp[ss * sstr + base];

  for (int t = 0; t < W_; ++t) {
    float nx = 0.f;
    if (t + 1 < W_) {                         // prefetch next step's G
#pragma unroll
      for (int ss = 0; ss < S; ++ss)
        nx += Gp[ss * sstr + base + (size_t)(t + 1) * K4H];
    }
    float a0 = p + bk, a1 = 0.f, a2 = 0.f, a3 = 0.f;
#pragma unroll
    for (int j = 0; j < 64; j += 4) {         // 4 independent FMA chains
      a0 = fmaf(bcastlane(h, j),     wc[j],     a0);
      a1 = fmaf(bcastlane(h, j + 1), wc[j + 1], a1);
      a2 = fmaf(bcastlane(h, j + 2), wc[j + 2], a2);
      a3 = fmaf(bcastlane(h, j + 3), wc[j + 3], a3);
    }
    float g = (a0 + a1) + (a2 + a3);
    float act = (w == 2) ? tanh_f(g) : sigm(g);   // wave-uniform branch
    sact[t & 1][w][u] = act;
    __syncthreads();                          // the single barrier per step
    float si = sact[t & 1][0][u];
    float sf = sact[t & 1][1][u];
    float tg = sact[t & 1][2][u];
    float so = sact[t & 1][3][u];
    c = fmaf(sf, c, si * tg);                 // replicated in all 4 waves
    h = so * tanh_f(c);
    if (w == 0) out[((size_t)b * W_ + t) * H_ + u] = c;  // cell state out
    p = nx;
  }
}

// ---------------------------------------------------------------------------
extern "C" void kernel_launch(void* const* d_in, const int* in_sizes, int n_in,
                              void* d_out, int out_size, void* d_ws, size_t ws_size,
                              hipStream_t stream) {
  // 0:x 1:W_state 2:b_state 3:W_in 4:w_attn 5:b_attn 6:Wx 7:Wh 8:b_lstm
  const float* x      = (const float*)d_in[0];
  const float* Wx     = (const float*)d_in[6];
  const float* Wh     = (const float*)d_in[7];
  const float* b_lstm = (const float*)d_in[8];
  float* out = (float*)d_out;

  const size_t gbytes = (size_t)M_ * K4H * sizeof(float);  // 4 MB per partial

  if (ws_size >= 4 * gbytes + (1u << 20)) {     // S = 4: 256 gemm blocks
    float*    Gp = (float*)d_ws;
    unsigned* B2 = (unsigned*)((char*)d_ws + 4 * gbytes);
    conv_w      <<<dim3(64),       dim3(256), 0, stream>>>(Wx, B2);
    gemm_mfma<4><<<dim3(32, 2, 4), dim3(256), 0, stream>>>(x, B2, Gp);
    lstm_seq<4> <<<dim3(B_),       dim3(256), 0, stream>>>(Gp, Wh, b_lstm, out);
  } else if (ws_size >= 2 * gbytes + (1u << 20)) {  // S = 2
    float*    Gp = (float*)d_ws;
    unsigned* B2 = (unsigned*)((char*)d_ws + 2 * gbytes);
    conv_w      <<<dim3(64),       dim3(256), 0, stream>>>(Wx, B2);
    gemm_mfma<2><<<dim3(32, 2, 2), dim3(256), 0, stream>>>(x, B2, Gp);
    lstm_seq<2> <<<dim3(B_),       dim3(256), 0, stream>>>(Gp, Wh, b_lstm, out);
  } else {                                      // S = 1 fallback (5 MB ws)
    float*    Gp = (float*)d_ws;
    unsigned* B2 = (unsigned*)((char*)d_ws + gbytes);
    conv_w      <<<dim3(64),       dim3(256), 0, stream>>>(Wx, B2);
    gemm_mfma<1><<<dim3(32, 2, 1), dim3(256), 0, stream>>>(x, B2, Gp);
    lstm_seq<1> <<<dim3(B_),       dim3(256), 0, stream>>>(Gp, Wh, b_lstm, out);
  }
}